// Round 13
// baseline (384.109 us; speedup 1.0000x reference)
//
#include <hip/hip_runtime.h>
#include <cstdint>

typedef unsigned short u16;
typedef unsigned int   u32;
typedef float  f32x4  __attribute__((ext_vector_type(4)));
typedef short  short8 __attribute__((ext_vector_type(8)));

__device__ inline float bf2f(u16 b){ u32 u=((u32)b)<<16; float f; __builtin_memcpy(&f,&u,4); return f; }
__device__ inline u16 f2bf(float f){ u32 u; __builtin_memcpy(&u,&f,4); u32 r=u+0x7FFFu+((u>>16)&1u); return (u16)(r>>16); }
__device__ inline float ubits(u32 u){ float f; __builtin_memcpy(&f,&u,4); return f; }
// truncating pack (1 op)
__device__ inline u32 pk(float hi, float lo){ u32 a,b; __builtin_memcpy(&a,&hi,4); __builtin_memcpy(&b,&lo,4); return __builtin_amdgcn_perm(a,b,0x07060302u); }
// RNE pack via HW: dst.lo16 = bf16(lo), dst.hi16 = bf16(hi) — 1 op vs ~16
__device__ inline u32 cvtpk(float lo, float hi){ u32 r; asm("v_cvt_pk_bf16_f32 %0, %1, %2" : "=v"(r) : "v"(lo), "v"(hi)); return r; }
__device__ inline void gload_lds16(const void* g, void* l){
  __builtin_amdgcn_global_load_lds((const __attribute__((address_space(1))) unsigned int*)g,
                                   (__attribute__((address_space(3))) unsigned int*)l, 16, 0, 0);
}

// counted-vmcnt barrier (T4)
#define CBAR(K) do{ asm volatile("s_waitcnt vmcnt(" #K ") lgkmcnt(0)" ::: "memory"); \
  __builtin_amdgcn_s_barrier(); __builtin_amdgcn_sched_barrier(0); }while(0)

// ---------------------------------------------------------------------------
// prep (unchanged — staged-order weight images):
//  tile t (of 16, 32 k each) = 16384 u16 = 256 lines x 128B.
//  decode of u16 offset o: line=o>>6, w=o&63, slot=w>>3, i=w&7,
//    c8 = slot ^ (line&7), n = 2*line + (c8>>2), g = c8&3.
//  Wt_in3 value = bf16(W_in[k][n]),  k = t*32 + g*8 + i      (linear k)
//  Wt_hd3 value = bf16(W_head[k][n]), k = t*32 + sigma(g,i)  (sigma-permuted)
//  gw1f: S-MFMA B-frags [8d][16c][4g][5col][8i] (2560/depth)
//  updA: update A-frags [8d][32t][16m][8sl]     (4096/depth)
// ---------------------------------------------------------------------------
__global__ __launch_bounds__(256) void prep_k(
    const float* __restrict__ W_in, const float* __restrict__ W_head,
    const float* __restrict__ ln_g, const float* __restrict__ W1,
    const float* __restrict__ W2, const float* __restrict__ b2,
    u16* __restrict__ Wt_in3, u16* __restrict__ Wt_hd3,
    u16* __restrict__ gw1f, u16* __restrict__ updA)
{
  int idx = blockIdx.x * 256 + threadIdx.x;
  if (idx < 524288){
    int which = idx >> 18;            // 0: W_in, 1: W_head
    int q = idx & 262143;
    int t = q >> 14, o = q & 16383;
    int line = o >> 6, w = o & 63, slot = w >> 3, i = w & 7;
    int c8 = slot ^ (line & 7);
    int n = 2 * line + (c8 >> 2);
    int g = c8 & 3;
    if (which == 0){
      int k = t * 32 + g * 8 + i;
      Wt_in3[q] = f2bf(W_in[k * 512 + n]);
    } else {
      int k = t * 32 + (i < 4 ? 4 * g + i : 12 + 4 * g + i);
      Wt_hd3[q] = f2bf(W_head[k * 512 + n]);
    }
  } else if (idx < 544768){
    int q = idx - 524288;                 // 8*2560
    int d = q / 2560, r = q % 2560;
    int c = r / 160, r2 = r % 160;
    int g = r2 / 40, r3 = r2 % 40;
    int col = r3 >> 3, i = r3 & 7;
    int k = 32 * c + (i < 4 ? 4 * g + i : 12 + 4 * g + i);
    u16 v;
    if (col == 4) v = 0x3F80u;
    else          v = f2bf(ln_g[d * 512 + k] * W1[(d * 512 + k) * 4 + col]);
    gw1f[q] = v;
  } else if (idx < 577536){
    int q = idx - 544768;                 // 8*4096
    int d = q >> 12, r = q & 4095;
    int t = r >> 7, r2 = r & 127;
    int m = r2 >> 3, sl = r2 & 7;
    int k = 16 * t + m;
    u16 v = 0;
    if (sl < 4)       v = f2bf(W2[(d * 4 + sl) * 512 + k]);
    else if (sl == 4) v = f2bf(b2[d * 512 + k]);
    updA[q] = v;
  }
}

// U[d][e] = sum_k bf16(g*W1); V = sum ln_b*W1 + b1
__global__ __launch_bounds__(64) void uv_k(
    const float* __restrict__ ln_g, const float* __restrict__ ln_b,
    const float* __restrict__ W1, const float* __restrict__ b1,
    float* __restrict__ U, float* __restrict__ V)
{
  int d = blockIdx.x >> 2, e = blockIdx.x & 3;
  int lane = threadIdx.x;
  float u = 0.f, v = 0.f;
  for (int k = lane; k < 512; k += 64){
    float w = W1[(d * 512 + k) * 4 + e];
    u += bf2f(f2bf(ln_g[d * 512 + k] * w));
    v += ln_b[d * 512 + k] * w;
  }
  for (int m = 1; m < 64; m <<= 1){ u += __shfl_xor(u, m); v += __shfl_xor(v, m); }
  if (lane == 0){ U[d * 4 + e] = u; V[d * 4 + e] = v + b1[d * 4 + e]; }
}

// ---------------------------------------------------------------------------
// fused v8: 64 rows/block, 4 waves (256 thr), wave = nq (k/n-quarter).
// LDS = exactly 80K -> 2 independent blocks/CU (same 8 waves/CU as r12's reg
// ceiling allows, but in TWO barrier domains: one block's drains overlap the
// other's MFMAs). Per-output accumulation order identical to r12.
// hv[q][c2][half][r] = h[row = 64*blk + q*16 + m][k = nq*128+c2*32+half*16+4g+r]
// LDS regions (temporally disjoint overlays, race-audited):
//   [0,65536)       tb0/tb1 weight dbuf (A and C)
//   [32768,59392)   mid weight dbuf 2x13312 [mid only; inside tb1]
//   [65536,73728)   hx h-broadcast 2x4096   [phase C only]
//   [73728,79872)   sS partials [4q][4nq][6][16] f32 [mid only]
//   [79872,80896)   zbuf (64 rows x f32x4)  [mid only]
//   [80896,81168)   sUV + sZ                [mid only]
// ---------------------------------------------------------------------------
__global__ __launch_bounds__(256, 2) void fused_k(
    const float* __restrict__ x, const u16* __restrict__ Wt_in3,
    const float* __restrict__ b_in, const u16* __restrict__ Wt_hd3,
    const float* __restrict__ b_head, const u16* __restrict__ gw1f,
    const u16* __restrict__ updA, const float* __restrict__ U,
    const float* __restrict__ V, float* __restrict__ out)
{
  __shared__ __align__(16) char LT[81920];
  constexpr int MIDB = 32768;    // mid dbuf base (stride 13312)
  constexpr int HXo  = 65536;    // h broadcast dbuf (2 x 4096)
  constexpr int SSo  = 73728, ZBo = 79872, UVo = 80896, SZo = 81152;
  float* sSf = (float*)(LT + SSo);
  float* zbf = (float*)(LT + ZBo);
  float* sUV = (float*)(LT + UVo);
  u16*   sZ  = (u16*)(LT + SZo);

  const int tid  = threadIdx.x;
  const int lane = tid & 63;
  const int m    = lane & 15;
  const int g    = lane >> 4;
  const int nq   = tid >> 6;     // wave id = k/n-quarter
  const size_t rowbase = (size_t)blockIdx.x * 64;

  if (tid < 32) sUV[tid] = U[tid];
  else if (tid < 64) sUV[tid] = V[tid - 32];
  if (tid >= 64 && tid < 72) sZ[tid - 64] = 0;

  auto stageA = [&](const u16* W, int t, char* dst){    // 8 loads/thread
    const char* src = (const char*)(W + t * 16384) + tid * 16;
    char* d2 = dst + tid * 16;
    #pragma unroll
    for (int j = 0; j < 8; ++j)
      gload_lds16(src + j * 4096, d2 + j * 4096);
  };
  auto stageM = [&](int d, int bf2){                    // <=4 loads/thread
    char* dsg = LT + MIDB + bf2 * 13312;
    const char* gs = (const char*)gw1f + d * 5120;
    gload_lds16(gs + tid * 16, dsg + tid * 16);
    if (tid < 64) gload_lds16(gs + 4096 + tid * 16, dsg + 4096 + tid * 16);
    const char* as = (const char*)updA + d * 8192;
    gload_lds16(as + tid * 16, dsg + 5120 + tid * 16);
    gload_lds16(as + 4096 + tid * 16, dsg + 5120 + 4096 + tid * 16);
  };

  auto mkfrag = [&](f32x4 a, f32x4 b)->short8{     // RNE via v_cvt_pk
    union{u32 u[4]; short8 s;} t;
    t.u[0]=cvtpk(a[0],a[1]); t.u[1]=cvtpk(a[2],a[3]);
    t.u[2]=cvtpk(b[0],b[1]); t.u[3]=cvtpk(b[2],b[3]);
    return t.s;
  };
  auto mkfragT = [&](f32x4 a, f32x4 b)->short8{    // trunc (r12 mid path)
    union{u32 u[4]; short8 s;} t;
    t.u[0]=pk(a[1],a[0]); t.u[1]=pk(a[3],a[2]);
    t.u[2]=pk(b[1],b[0]); t.u[3]=pk(b[3],b[2]);
    return t.s;
  };

  // A-frag byte base inside a staged tile (conflict-light pattern)
  const int afoff = (m >> 1) * 128 + (((((m & 1) << 2) | g) ^ ((m >> 1) & 7)) << 4);

  // ================= phase A: h = relu(x @ W_in + b_in) =================
  f32x4 hv[4][4][2];
  #pragma unroll
  for (int q = 0; q < 4; ++q)
    #pragma unroll
    for (int c2 = 0; c2 < 4; ++c2){ hv[q][c2][0] = (f32x4)0.f; hv[q][c2][1] = (f32x4)0.f; }

  const float* xbase = x + (rowbase + m) * 512 + g * 8;
  f32x4 xv[4][2];
  #pragma unroll
  for (int q = 0; q < 4; ++q){
    xv[q][0] = *(const f32x4*)(xbase + q * 8192);
    xv[q][1] = *(const f32x4*)(xbase + q * 8192 + 4);
  }
  stageA(Wt_in3, 0, LT);
  __syncthreads();

  // Body t: stage(t+1)->tb[(t+1)&1] ; bq=pack(x(t)) ; load x(t+1) ; 32 MFMA
  // on tb[t&1] ; CBAR(8) keeps x(t+1), drains stage(t+1) (needed next body).
  #pragma unroll 2
  for (int t = 0; t < 16; ++t){
    if (t < 15) stageA(Wt_in3, t + 1, LT + ((t + 1) & 1) * 32768);
    short8 bq[4];
    #pragma unroll
    for (int q = 0; q < 4; ++q) bq[q] = mkfrag(xv[q][0], xv[q][1]);
    if (t < 15){
      #pragma unroll
      for (int q = 0; q < 4; ++q){
        xv[q][0] = *(const f32x4*)(xbase + q * 8192 + (t + 1) * 32);
        xv[q][1] = *(const f32x4*)(xbase + q * 8192 + (t + 1) * 32 + 4);
      }
    }
    const char* wb = LT + (t & 1) * 32768 + nq * 8192 + afoff;
    #pragma unroll
    for (int f = 0; f < 8; ++f){
      short8 aw = *(const short8*)(wb + f * 1024);
      #pragma unroll
      for (int q = 0; q < 4; ++q)
        hv[q][f >> 1][f & 1] =
          __builtin_amdgcn_mfma_f32_16x16x32_bf16(aw, bq[q], hv[q][f >> 1][f & 1], 0, 0, 0);
    }
    if (t < 15) CBAR(8);
  }
  __syncthreads();   // all waves done reading tb1 before mid overlays it

  // epilogue: +bias, relu, RNE-round to bf16 values (cvt_pk pairs)
  #pragma unroll
  for (int q = 0; q < 4; ++q)
    #pragma unroll
    for (int c2 = 0; c2 < 4; ++c2)
      #pragma unroll
      for (int hf = 0; hf < 2; ++hf){
        f32x4 bi = *(const f32x4*)(b_in + nq * 128 + c2 * 32 + hf * 16 + g * 4);
        f32x4 v;
        #pragma unroll
        for (int r = 0; r < 4; ++r){ float w = hv[q][c2][hf][r] + bi[r]; v[r] = w > 0.f ? w : 0.f; }
        u32 ua = cvtpk(v[0], v[1]), ub = cvtpk(v[2], v[3]);
        hv[q][c2][hf][0] = ubits(ua << 16);
        hv[q][c2][hf][1] = ubits(ua & 0xFFFF0000u);
        hv[q][c2][hf][2] = ubits(ub << 16);
        hv[q][c2][hf][3] = ubits(ub & 0xFFFF0000u);
      }

  stageM(0, 0);       // writes [32768,46080) — tb1 reads all done (barrier above)
  __syncthreads();

  // ================= mid: 8 residual MLP blocks (n-split) =================
  int buf = 0;
  #pragma unroll 1
  for (int d = 0; d < 8; ++d){
    if (d < 7) stageM(d + 1, buf ^ 1);
    else       stageA(Wt_hd3, 0, LT);          // prefetch C tile 0 into tb0 (mid never reads tb0)

    const u16* sGp = (const u16*)(LT + MIDB + buf * 13312);
    const u16* sAp = sGp + 2560;

    // ---- per-slice S + sum(ones col) + Gram(sumsq)
    const u16* gb = (m < 5) ? (sGp + nq * 640 + g * 40 + m * 8) : sZ;
    const int gstep = (m < 5) ? 160 : 0;
    f32x4 aS[4], aG[4];
    #pragma unroll
    for (int q = 0; q < 4; ++q){ aS[q] = (f32x4)0.f; aG[q] = (f32x4)0.f; }
    #pragma unroll
    for (int c2 = 0; c2 < 4; ++c2){
      short8 bf = *(const short8*)(gb + c2 * gstep);
      #pragma unroll
      for (int q = 0; q < 4; ++q){
        short8 af = mkfragT(hv[q][c2][0], hv[q][c2][1]);
        aS[q] = __builtin_amdgcn_mfma_f32_16x16x32_bf16(af, bf, aS[q], 0, 0, 0);
        aG[q] = __builtin_amdgcn_mfma_f32_16x16x32_bf16(af, af, aG[q], 0, 0, 0);
      }
    }

    // ---- write per-slice partials: [q][nq][e=0..5][16 batch]
    #pragma unroll
    for (int q = 0; q < 4; ++q){
      if (m < 5)
        *(f32x4*)(sSf + ((q * 4 + nq) * 6 + m) * 16 + 4 * g) = aS[q];
      if ((m >> 2) == g)
        sSf[((q * 4 + nq) * 6 + 5) * 16 + m] = aG[q][m & 3];
    }
    CBAR(8);   // keep next-depth stage in flight; lgkm0 publishes sSf

    // ---- z for all 64 rows (threads 0..63)
    if (tid < 64){
      int q2 = tid >> 4, b = tid & 15;
      float S0 = 0.f, S1 = 0.f, S2 = 0.f, S3 = 0.f, sm = 0.f, sq = 0.f;
      #pragma unroll
      for (int nn = 0; nn < 4; ++nn){
        const float* pp = sSf + ((q2 * 4 + nn) * 6) * 16 + b;
        S0 += pp[0]; S1 += pp[16]; S2 += pp[32]; S3 += pp[48];
        sm += pp[64]; sq += pp[80];
      }
      float mu  = sm * (1.f / 512.f);
      float var = sq * (1.f / 512.f) - mu * mu;
      float rs  = rsqrtf(var + 1e-5f);
      f32x4 zz;
      float z0 = fmaf(rs, S0 - mu * sUV[d * 4 + 0], sUV[32 + d * 4 + 0]);
      float z1 = fmaf(rs, S1 - mu * sUV[d * 4 + 1], sUV[32 + d * 4 + 1]);
      float z2 = fmaf(rs, S2 - mu * sUV[d * 4 + 2], sUV[32 + d * 4 + 2]);
      float z3 = fmaf(rs, S3 - mu * sUV[d * 4 + 3], sUV[32 + d * 4 + 3]);
      zz[0] = z0 > 0.f ? z0 : 0.f;
      zz[1] = z1 > 0.f ? z1 : 0.f;
      zz[2] = z2 > 0.f ? z2 : 0.f;
      zz[3] = z3 > 0.f ? z3 : 0.f;
      *(f32x4*)(zbf + tid * 4) = zz;
    }
    CBAR(8);   // publish zbf, keep stage in flight

    // ---- update: h += [W2|b2]^T [z|1] on own k-slice
    #pragma unroll
    for (int q = 0; q < 4; ++q){
      f32x4 z4 = *(const f32x4*)(zbf + (q * 16 + m) * 4);
      union{u32 u[4]; short8 s;} bz;
      bz.u[0] = (g == 0) ? pk(z4[1], z4[0]) : 0u;
      bz.u[1] = (g == 0) ? pk(z4[3], z4[2]) : 0u;
      bz.u[2] = (g == 0) ? 0x00003F80u : 0u;
      bz.u[3] = 0u;
      const u16* ab = (g == 0) ? (sAp + nq * 1024 + m * 8) : sZ;
      const int ainc = (g == 0) ? 128 : 0;
      #pragma unroll
      for (int t2 = 0; t2 < 8; ++t2){
        short8 aw = *(const short8*)(ab + t2 * ainc);
        hv[q][t2 >> 1][t2 & 1] =
          __builtin_amdgcn_mfma_f32_16x16x32_bf16(aw, bz.s, hv[q][t2 >> 1][t2 & 1], 0, 0, 0);
      }
    }
    __syncthreads();   // full drain: protects mid dbuf rotation (and d7 stageA)
    buf ^= 1;
  }

  // ================= phase C: out = h @ W_head + b_head ===================
  // pack h (RNE — pipeline's final h rounding); hv dead afterwards
  short8 p[4][4];
  #pragma unroll
  for (int q = 0; q < 4; ++q)
    #pragma unroll
    for (int c2 = 0; c2 < 4; ++c2)
      p[q][c2] = mkfrag(hv[q][c2][0], hv[q][c2][1]);

  f32x4 acc[4][8];
  #pragma unroll
  for (int q = 0; q < 4; ++q)
    #pragma unroll
    for (int of = 0; of < 8; ++of) acc[q][of] = (f32x4)0.f;

  // prologue: broadcast chunk 0 (owner nq==0); stage tile 1 into tb1
  if (nq == 0){
    #pragma unroll
    for (int q = 0; q < 4; ++q)
      *(short8*)(LT + HXo + (q * 64 + m * 4 + g) * 16) = p[q][0];
  }
  stageA(Wt_hd3, 1, LT + 32768);
  CBAR(8);   // keep stage(1) in flight; publish hx

  // Body c: (c>=1) stage(c+1)->tb[(c+1)&1] ; hx-write chunk c+1 (owner) ;
  // read tb[c&1]+hx[c&1] ; CBAR(0) drains stage (aged ~1 body; sibling block
  // hides the remainder).
  #pragma unroll 2
  for (int c = 0; c < 16; ++c){
    if (c >= 1 && c < 15) stageA(Wt_hd3, c + 1, LT + ((c + 1) & 1) * 32768);
    if (c < 15 && nq == ((c + 1) >> 2)){
      #pragma unroll
      for (int q = 0; q < 4; ++q)
        *(short8*)(LT + HXo + ((c + 1) & 1) * 4096 + (q * 64 + m * 4 + g) * 16)
          = p[q][(c + 1) & 3];
    }
    const char* hxb = LT + HXo + (c & 1) * 4096 + (m * 4 + g) * 16;
    short8 bh[4];
    #pragma unroll
    for (int q = 0; q < 4; ++q) bh[q] = *(const short8*)(hxb + q * 1024);
    const char* wb = LT + (c & 1) * 32768 + nq * 8192 + afoff;
    #pragma unroll
    for (int of = 0; of < 8; ++of){
      short8 aw = *(const short8*)(wb + of * 1024);
      #pragma unroll
      for (int q = 0; q < 4; ++q)
        acc[q][of] = __builtin_amdgcn_mfma_f32_16x16x32_bf16(aw, bh[q], acc[q][of], 0, 0, 0);
    }
    if (c < 15) CBAR(0);
  }

  // epilogue: +bias, store
  #pragma unroll
  for (int q = 0; q < 4; ++q)
    #pragma unroll
    for (int of = 0; of < 8; ++of){
      f32x4 bhd = *(const f32x4*)(b_head + nq * 128 + of * 16 + g * 4);
      f32x4 v;
      #pragma unroll
      for (int r = 0; r < 4; ++r) v[r] = acc[q][of][r] + bhd[r];
      *(f32x4*)(out + (rowbase + q * 16 + m) * 512 + nq * 128 + of * 16 + g * 4) = v;
    }
}

// ---------------------------------------------------------------------------
extern "C" void kernel_launch(void* const* d_in, const int* in_sizes, int n_in,
                              void* d_out, int out_size, void* d_ws, size_t ws_size,
                              hipStream_t stream)
{
  const float* x      = (const float*)d_in[0];
  const float* W_in   = (const float*)d_in[1];
  const float* b_in   = (const float*)d_in[2];
  const float* ln_g   = (const float*)d_in[3];
  const float* ln_b   = (const float*)d_in[4];
  const float* W1     = (const float*)d_in[5];
  const float* b1     = (const float*)d_in[6];
  const float* W2     = (const float*)d_in[7];
  const float* b2     = (const float*)d_in[8];
  const float* W_head = (const float*)d_in[9];
  const float* b_head = (const float*)d_in[10];
  float* out = (float*)d_out;
  const int B = in_sizes[0] / 512;

  char* ws = (char*)d_ws;
  u16*   Wt_in3 = (u16*)ws;                 // 262144
  u16*   Wt_hd3 = Wt_in3 + 262144;          // 262144
  u16*   gw1f   = Wt_hd3 + 262144;          // 20480
  u16*   updA   = gw1f + 20480;             // 32768
  float* Up     = (float*)(updA + 32768);   // 32
  float* Vp     = Up + 32;                  // 32

  prep_k<<<2256, 256, 0, stream>>>(W_in, W_head, ln_g, W1, W2, b2, Wt_in3, Wt_hd3, gw1f, updA);
  uv_k<<<32, 64, 0, stream>>>(ln_g, ln_b, W1, b1, Up, Vp);
  fused_k<<<B / 64, 256, 0, stream>>>(x, Wt_in3, b_in, Wt_hd3, b_head, gw1f, updA, Up, Vp, out);
}

// Round 14
// 338.223 us; speedup vs baseline: 1.1357x; 1.1357x over previous
//
#include <hip/hip_runtime.h>
#include <cstdint>

typedef unsigned short u16;
typedef unsigned int   u32;
typedef float  f32x4  __attribute__((ext_vector_type(4)));
typedef short  short8 __attribute__((ext_vector_type(8)));

__device__ inline float bf2f(u16 b){ u32 u=((u32)b)<<16; float f; __builtin_memcpy(&f,&u,4); return f; }
__device__ inline u16 f2bf(float f){ u32 u; __builtin_memcpy(&u,&f,4); u32 r=u+0x7FFFu+((u>>16)&1u); return (u16)(r>>16); }
__device__ inline float ubits(u32 u){ float f; __builtin_memcpy(&f,&u,4); return f; }
// truncating pack (1 op; exact when inputs already bf16-valued)
__device__ inline u32 pk(float hi, float lo){ u32 a,b; __builtin_memcpy(&a,&hi,4); __builtin_memcpy(&b,&lo,4); return __builtin_amdgcn_perm(a,b,0x07060302u); }
// RNE pack via HW: dst.lo16=bf16(lo), dst.hi16=bf16(hi) — 1 op (r13-validated bit-exact vs pkr)
__device__ inline u32 cvtpk(float lo, float hi){ u32 r; asm("v_cvt_pk_bf16_f32 %0, %1, %2" : "=v"(r) : "v"(lo), "v"(hi)); return r; }
__device__ inline void gload_lds16(const void* g, void* l){
  __builtin_amdgcn_global_load_lds((const __attribute__((address_space(1))) unsigned int*)g,
                                   (__attribute__((address_space(3))) unsigned int*)l, 16, 0, 0);
}

// counted-vmcnt barrier (T4)
#define CBAR(K) do{ asm volatile("s_waitcnt vmcnt(" #K ") lgkmcnt(0)" ::: "memory"); \
  __builtin_amdgcn_s_barrier(); __builtin_amdgcn_sched_barrier(0); }while(0)

// ---------------------------------------------------------------------------
// prep (unchanged — staged-order weight images):
//  tile t (of 16, 32 k each) = 16384 u16 = 256 lines x 128B.
//  decode of u16 offset o: line=o>>6, w=o&63, slot=w>>3, i=w&7,
//    c8 = slot ^ (line&7), n = 2*line + (c8>>2), g = c8&3.
//  Wt_in3 value = bf16(W_in[k][n]),  k = t*32 + g*8 + i      (linear k)
//  Wt_hd3 value = bf16(W_head[k][n]), k = t*32 + sigma(g,i)  (sigma-permuted)
//  gw1f: S-MFMA B-frags [8d][16c][4g][5col][8i] (2560/depth)
//  updA: update A-frags [8d][32t][16m][8sl]     (4096/depth)
// ---------------------------------------------------------------------------
__global__ __launch_bounds__(256) void prep_k(
    const float* __restrict__ W_in, const float* __restrict__ W_head,
    const float* __restrict__ ln_g, const float* __restrict__ W1,
    const float* __restrict__ W2, const float* __restrict__ b2,
    u16* __restrict__ Wt_in3, u16* __restrict__ Wt_hd3,
    u16* __restrict__ gw1f, u16* __restrict__ updA)
{
  int idx = blockIdx.x * 256 + threadIdx.x;
  if (idx < 524288){
    int which = idx >> 18;            // 0: W_in, 1: W_head
    int q = idx & 262143;
    int t = q >> 14, o = q & 16383;
    int line = o >> 6, w = o & 63, slot = w >> 3, i = w & 7;
    int c8 = slot ^ (line & 7);
    int n = 2 * line + (c8 >> 2);
    int g = c8 & 3;
    if (which == 0){
      int k = t * 32 + g * 8 + i;
      Wt_in3[q] = f2bf(W_in[k * 512 + n]);
    } else {
      int k = t * 32 + (i < 4 ? 4 * g + i : 12 + 4 * g + i);
      Wt_hd3[q] = f2bf(W_head[k * 512 + n]);
    }
  } else if (idx < 544768){
    int q = idx - 524288;                 // 8*2560
    int d = q / 2560, r = q % 2560;
    int c = r / 160, r2 = r % 160;
    int g = r2 / 40, r3 = r2 % 40;
    int col = r3 >> 3, i = r3 & 7;
    int k = 32 * c + (i < 4 ? 4 * g + i : 12 + 4 * g + i);
    u16 v;
    if (col == 4) v = 0x3F80u;
    else          v = f2bf(ln_g[d * 512 + k] * W1[(d * 512 + k) * 4 + col]);
    gw1f[q] = v;
  } else if (idx < 577536){
    int q = idx - 544768;                 // 8*4096
    int d = q >> 12, r = q & 4095;
    int t = r >> 7, r2 = r & 127;
    int m = r2 >> 3, sl = r2 & 7;
    int k = 16 * t + m;
    u16 v = 0;
    if (sl < 4)       v = f2bf(W2[(d * 4 + sl) * 512 + k]);
    else if (sl == 4) v = f2bf(b2[d * 512 + k]);
    updA[q] = v;
  }
}

// U[d][e] = sum_k bf16(g*W1); V = sum ln_b*W1 + b1
__global__ __launch_bounds__(64) void uv_k(
    const float* __restrict__ ln_g, const float* __restrict__ ln_b,
    const float* __restrict__ W1, const float* __restrict__ b1,
    float* __restrict__ U, float* __restrict__ V)
{
  int d = blockIdx.x >> 2, e = blockIdx.x & 3;
  int lane = threadIdx.x;
  float u = 0.f, v = 0.f;
  for (int k = lane; k < 512; k += 64){
    float w = W1[(d * 512 + k) * 4 + e];
    u += bf2f(f2bf(ln_g[d * 512 + k] * w));
    v += ln_b[d * 512 + k] * w;
  }
  for (int m = 1; m < 64; m <<= 1){ u += __shfl_xor(u, m); v += __shfl_xor(v, m); }
  if (lane == 0){ U[d * 4 + e] = u; V[d * 4 + e] = v + b1[d * 4 + e]; }
}

// ---------------------------------------------------------------------------
// fused v9: r12 geometry (128 rows/block, 8 waves/512 thr, nq/rh split,
// (512,2)) + (1) cvt_pk_bf16_f32 for all RNE packs, (2) mid 3-buffer/2-deep
// prefetch with counted barriers CBAR(8)/CBAR(8)/CBAR(1), (3) head tiles 0,1
// pre-staged during mid d6/d7.
// LDS (147728 B; overlays temporally disjoint, race-audited):
//   [0,98304)        tb0/1/2 weight tiles (A and C)
//   [65536,77824)    sS partials [mid only; tb2 dead]
//   [77824,79872)    zbuf        [mid only]
//   [98304,147456)   mid mbuf 3x16384 (gw1f 5120 + updA 8192) [mid only]
//   [98304,114688)   hx h-broadcast 2x8192 [phase C only; mbuf0 dead]
//   [147456,147728)  sUV + sZ (persistent)
// hv[q][c2][half][r] = h[row=rh*64+q*16+m][k=nq*128+c2*32+half*16+4g+r]
// Mid depth-end CBAR(1): K=1 <= min per-thread loads issued this depth, so
// stage(d+1) is fully drained while stage(d+2) stays in flight.
// ---------------------------------------------------------------------------
__global__ __launch_bounds__(512, 2) void fused_k(
    const float* __restrict__ x, const u16* __restrict__ Wt_in3,
    const float* __restrict__ b_in, const u16* __restrict__ Wt_hd3,
    const float* __restrict__ b_head, const u16* __restrict__ gw1f,
    const u16* __restrict__ updA, const float* __restrict__ U,
    const float* __restrict__ V, float* __restrict__ out)
{
  __shared__ __align__(16) char LT[147728];
  constexpr int SSo = 65536, ZBo = 77824;
  constexpr int MIDB = 98304, HXo = 98304;
  constexpr int UVo = 147456, SZo = 147712;
  float* sSf = (float*)(LT + SSo);
  float* zbf = (float*)(LT + ZBo);
  float* sUV = (float*)(LT + UVo);
  u16*   sZ  = (u16*)(LT + SZo);

  const int tid  = threadIdx.x;
  const int wv   = tid >> 6;
  const int lane = tid & 63;
  const int m    = lane & 15;
  const int g    = lane >> 4;
  const int nq   = wv & 3;
  const int rh   = wv >> 2;
  const size_t rowbase = (size_t)blockIdx.x * 128 + rh * 64;

  if (tid < 32) sUV[tid] = U[tid];
  else if (tid < 64) sUV[tid] = V[tid - 32];
  if (tid >= 64 && tid < 72) sZ[tid - 64] = 0;

  auto stageA = [&](const u16* W, int t, char* dst){   // 4 loads/thread
    const char* src = (const char*)(W + t * 16384) + tid * 16;
    char* d2 = dst + tid * 16;
    #pragma unroll
    for (int j = 0; j < 4; ++j)
      gload_lds16(src + j * 8192, d2 + j * 8192);
  };
  auto stageM = [&](int d, int bf3){                   // 1-2 loads/thread
    char* dsg = LT + MIDB + bf3 * 16384;
    if (tid < 320)
      gload_lds16((const char*)gw1f + d * 5120 + tid * 16, dsg + tid * 16);
    gload_lds16((const char*)updA + d * 8192 + tid * 16, dsg + 5120 + tid * 16);
  };

  auto mkfrag = [&](f32x4 a, f32x4 b)->short8{     // RNE via v_cvt_pk
    union{u32 u[4]; short8 s;} t;
    t.u[0]=cvtpk(a[0],a[1]); t.u[1]=cvtpk(a[2],a[3]);
    t.u[2]=cvtpk(b[0],b[1]); t.u[3]=cvtpk(b[2],b[3]);
    return t.s;
  };
  auto mkfragT = [&](f32x4 a, f32x4 b)->short8{    // trunc (mid path)
    union{u32 u[4]; short8 s;} t;
    t.u[0]=pk(a[1],a[0]); t.u[1]=pk(a[3],a[2]);
    t.u[2]=pk(b[1],b[0]); t.u[3]=pk(b[3],b[2]);
    return t.s;
  };

  // A-frag byte base inside a staged tile (conflict-light pattern)
  const int afoff = (m >> 1) * 128 + (((((m & 1) << 2) | g) ^ ((m >> 1) & 7)) << 4);

  // ================= phase A: h = relu(x @ W_in + b_in) =================
  f32x4 hv[4][4][2];
  #pragma unroll
  for (int q = 0; q < 4; ++q)
    #pragma unroll
    for (int c2 = 0; c2 < 4; ++c2){ hv[q][c2][0] = (f32x4)0.f; hv[q][c2][1] = (f32x4)0.f; }

  const float* xbase = x + (rowbase + m) * 512 + g * 8;
  f32x4 xA[4][2], xB[4][2];
  #pragma unroll
  for (int q = 0; q < 4; ++q){
    xA[q][0] = *(const f32x4*)(xbase + q * 8192);
    xA[q][1] = *(const f32x4*)(xbase + q * 8192 + 4);
    xB[q][0] = *(const f32x4*)(xbase + q * 8192 + 32);
    xB[q][1] = *(const f32x4*)(xbase + q * 8192 + 36);
  }
  stageA(Wt_in3, 0, LT);
  stageA(Wt_in3, 1, LT + 32768);
  __syncthreads();

  // Body t: stage(t+2)[4] ; bq=cvtpk(x(t)) ; reload x regs with x(t+2)[8] ;
  // 32 MFMA on tb[t%3] ; CBAR(20) keeps {stage(t+2),x(t+1),x(t+2)}, drains
  // stage(t+1). t=14: CBAR(8) keeps x(15). t=15: no barrier.
  #pragma unroll
  for (int t = 0; t < 16; ++t){
    if (t < 14) stageA(Wt_in3, t + 2, LT + ((t + 2) % 3) * 32768);
    short8 bq[4];
    #pragma unroll
    for (int q = 0; q < 4; ++q)
      bq[q] = (t & 1) ? mkfrag(xB[q][0], xB[q][1]) : mkfrag(xA[q][0], xA[q][1]);
    if (t < 14){
      #pragma unroll
      for (int q = 0; q < 4; ++q){
        if (t & 1){
          xB[q][0] = *(const f32x4*)(xbase + q * 8192 + (t + 2) * 32);
          xB[q][1] = *(const f32x4*)(xbase + q * 8192 + (t + 2) * 32 + 4);
        } else {
          xA[q][0] = *(const f32x4*)(xbase + q * 8192 + (t + 2) * 32);
          xA[q][1] = *(const f32x4*)(xbase + q * 8192 + (t + 2) * 32 + 4);
        }
      }
    }
    const char* wb = LT + (t % 3) * 32768 + nq * 8192 + afoff;
    #pragma unroll
    for (int f = 0; f < 8; ++f){
      short8 aw = *(const short8*)(wb + f * 1024);
      #pragma unroll
      for (int q = 0; q < 4; ++q)
        hv[q][f >> 1][f & 1] =
          __builtin_amdgcn_mfma_f32_16x16x32_bf16(aw, bq[q], hv[q][f >> 1][f & 1], 0, 0, 0);
    }
    if (t < 14)       CBAR(20);
    else if (t == 14) CBAR(8);
  }

  // epilogue: +bias, relu, RNE round to bf16 values (cvt_pk pairs)
  #pragma unroll
  for (int q = 0; q < 4; ++q)
    #pragma unroll
    for (int c2 = 0; c2 < 4; ++c2)
      #pragma unroll
      for (int hf = 0; hf < 2; ++hf){
        f32x4 bi = *(const f32x4*)(b_in + nq * 128 + c2 * 32 + hf * 16 + g * 4);
        f32x4 v;
        #pragma unroll
        for (int r = 0; r < 4; ++r){ float w = hv[q][c2][hf][r] + bi[r]; v[r] = w > 0.f ? w : 0.f; }
        u32 ua = cvtpk(v[0], v[1]), ub = cvtpk(v[2], v[3]);
        hv[q][c2][hf][0] = ubits(ua << 16);
        hv[q][c2][hf][1] = ubits(ua & 0xFFFF0000u);
        hv[q][c2][hf][2] = ubits(ub << 16);
        hv[q][c2][hf][3] = ubits(ub & 0xFFFF0000u);
      }

  // mid prologue: stage depths 0,1 behind a full barrier (race-free)
  stageM(0, 0);
  stageM(1, 1);
  __syncthreads();

  // ================= mid: 8 residual MLP blocks (3-buffer, 2-deep) ========
  #pragma unroll 1
  for (int d = 0; d < 8; ++d){
    if (d < 6)       stageM(d + 2, (d + 2) % 3);
    else if (d == 6) stageA(Wt_hd3, 0, LT);            // head tile 0 -> tb0
    else             stageA(Wt_hd3, 1, LT + 32768);    // head tile 1 -> tb1

    const u16* sGp = (const u16*)(LT + MIDB + (d % 3) * 16384);
    const u16* sAp = sGp + 2560;

    // ---- per-slice S + sum(ones col) + Gram(sumsq), 4 row-groups
    const u16* gb = (m < 5) ? (sGp + nq * 640 + g * 40 + m * 8) : sZ;
    const int gstep = (m < 5) ? 160 : 0;
    f32x4 aS[4], aG[4];
    #pragma unroll
    for (int q = 0; q < 4; ++q){ aS[q] = (f32x4)0.f; aG[q] = (f32x4)0.f; }
    #pragma unroll
    for (int c2 = 0; c2 < 4; ++c2){
      short8 bf = *(const short8*)(gb + c2 * gstep);
      #pragma unroll
      for (int q = 0; q < 4; ++q){
        short8 af = mkfragT(hv[q][c2][0], hv[q][c2][1]);
        aS[q] = __builtin_amdgcn_mfma_f32_16x16x32_bf16(af, bf, aS[q], 0, 0, 0);
        aG[q] = __builtin_amdgcn_mfma_f32_16x16x32_bf16(af, af, aG[q], 0, 0, 0);
      }
    }

    // ---- write per-slice partials: [rh][q][nq][e=0..5][16 batch]
    #pragma unroll
    for (int q = 0; q < 4; ++q){
      if (m < 5)
        *(f32x4*)(sSf + (((rh * 4 + q) * 4 + nq) * 6 + m) * 16 + 4 * g) = aS[q];
      if ((m >> 2) == g)
        sSf[(((rh * 4 + q) * 4 + nq) * 6 + 5) * 16 + m] = aG[q][m & 3];
    }
    CBAR(8);   // publish sSf (lgkm0); keep all staging in flight

    // ---- z for all 128 rows (threads 0..127)
    if (tid < 128){
      int rh2 = tid >> 6, rl = tid & 63, q2 = rl >> 4, b = rl & 15;
      float S0 = 0.f, S1 = 0.f, S2 = 0.f, S3 = 0.f, sm = 0.f, sq = 0.f;
      #pragma unroll
      for (int nn = 0; nn < 4; ++nn){
        const float* pp = sSf + (((rh2 * 4 + q2) * 4 + nn) * 6) * 16 + b;
        S0 += pp[0]; S1 += pp[16]; S2 += pp[32]; S3 += pp[48];
        sm += pp[64]; sq += pp[80];
      }
      float mu  = sm * (1.f / 512.f);
      float var = sq * (1.f / 512.f) - mu * mu;
      float rs  = rsqrtf(var + 1e-5f);
      f32x4 zz;
      float z0 = fmaf(rs, S0 - mu * sUV[d * 4 + 0], sUV[32 + d * 4 + 0]);
      float z1 = fmaf(rs, S1 - mu * sUV[d * 4 + 1], sUV[32 + d * 4 + 1]);
      float z2 = fmaf(rs, S2 - mu * sUV[d * 4 + 2], sUV[32 + d * 4 + 2]);
      float z3 = fmaf(rs, S3 - mu * sUV[d * 4 + 3], sUV[32 + d * 4 + 3]);
      zz[0] = z0 > 0.f ? z0 : 0.f;
      zz[1] = z1 > 0.f ? z1 : 0.f;
      zz[2] = z2 > 0.f ? z2 : 0.f;
      zz[3] = z3 > 0.f ? z3 : 0.f;
      *(f32x4*)(zbf + tid * 4) = zz;
    }
    CBAR(8);   // publish zbf; keep staging in flight

    // ---- update: h += [W2|b2]^T [z|1] on own k-slice
    #pragma unroll
    for (int q = 0; q < 4; ++q){
      f32x4 z4 = *(const f32x4*)(zbf + (rh * 64 + q * 16 + m) * 4);
      union{u32 u[4]; short8 s;} bz;
      bz.u[0] = (g == 0) ? pk(z4[1], z4[0]) : 0u;
      bz.u[1] = (g == 0) ? pk(z4[3], z4[2]) : 0u;
      bz.u[2] = (g == 0) ? 0x00003F80u : 0u;
      bz.u[3] = 0u;
      const u16* ab = (g == 0) ? (sAp + nq * 1024 + m * 8) : sZ;
      const int ainc = (g == 0) ? 128 : 0;
      #pragma unroll
      for (int t2 = 0; t2 < 8; ++t2){
        short8 aw = *(const short8*)(ab + t2 * ainc);
        hv[q][t2 >> 1][t2 & 1] =
          __builtin_amdgcn_mfma_f32_16x16x32_bf16(aw, bz.s, hv[q][t2 >> 1][t2 & 1], 0, 0, 0);
      }
    }
    // depth-end: drain stage(d+1) fully (issued last depth), keep newest 1
    // (part of this depth's stage; K=1 <= min loads/thread issued this depth)
    CBAR(1);
  }

  // ================= phase C: out = h @ W_head + b_head ===================
  // pack h (RNE via cvt_pk — pipeline's final h rounding)
  short8 p[4][4];
  #pragma unroll
  for (int q = 0; q < 4; ++q)
    #pragma unroll
    for (int c2 = 0; c2 < 4; ++c2)
      p[q][c2] = mkfrag(hv[q][c2][0], hv[q][c2][1]);

  f32x4 acc[4][8];
  #pragma unroll
  for (int q = 0; q < 4; ++q)
    #pragma unroll
    for (int of = 0; of < 8; ++of) acc[q][of] = (f32x4)0.f;

  // prologue: broadcast chunk 0 (tiles 0,1 already staged at mid d6/d7)
  if (nq == 0){
    #pragma unroll
    for (int q = 0; q < 4; ++q)
      *(short8*)(LT + HXo + rh * 4096 + (q * 64 + m * 4 + g) * 16) = p[q][0];
  }
  CBAR(8);   // publish hx; keep tile-1 staging remnants in flight

  // Body c: stage(c+2)[4] ; hx-write c+1 (owner) ; read tb[c%3]+hx[c&1] ;
  // CBAR(4) keeps stage(c+2), drains stage(c+1). c=14: CBAR(0). c=15: none.
  #pragma unroll
  for (int c = 0; c < 16; ++c){
    if (c < 14) stageA(Wt_hd3, c + 2, LT + ((c + 2) % 3) * 32768);
    if (c < 15 && nq == ((c + 1) >> 2)){
      #pragma unroll
      for (int q = 0; q < 4; ++q)
        *(short8*)(LT + HXo + ((c + 1) & 1) * 8192 + rh * 4096 + (q * 64 + m * 4 + g) * 16)
          = p[q][(c + 1) & 3];
    }
    const char* hxb = LT + HXo + (c & 1) * 8192 + rh * 4096 + (m * 4 + g) * 16;
    short8 bh[4];
    #pragma unroll
    for (int q = 0; q < 4; ++q) bh[q] = *(const short8*)(hxb + q * 1024);
    const char* wb = LT + (c % 3) * 32768 + nq * 8192 + afoff;
    #pragma unroll
    for (int of = 0; of < 8; ++of){
      short8 aw = *(const short8*)(wb + of * 1024);
      #pragma unroll
      for (int q = 0; q < 4; ++q)
        acc[q][of] = __builtin_amdgcn_mfma_f32_16x16x32_bf16(aw, bh[q], acc[q][of], 0, 0, 0);
    }
    if (c < 14)       CBAR(4);
    else if (c == 14) CBAR(0);
  }

  // epilogue: +bias, store
  #pragma unroll
  for (int q = 0; q < 4; ++q)
    #pragma unroll
    for (int of = 0; of < 8; ++of){
      f32x4 bhd = *(const f32x4*)(b_head + nq * 128 + of * 16 + g * 4);
      f32x4 v;
      #pragma unroll
      for (int r = 0; r < 4; ++r) v[r] = acc[q][of][r] + bhd[r];
      *(f32x4*)(out + (rowbase + q * 16 + m) * 512 + nq * 128 + of * 16 + g * 4) = v;
    }
}

// ---------------------------------------------------------------------------
extern "C" void kernel_launch(void* const* d_in, const int* in_sizes, int n_in,
                              void* d_out, int out_size, void* d_ws, size_t ws_size,
                              hipStream_t stream)
{
  const float* x      = (const float*)d_in[0];
  const float* W_in   = (const float*)d_in[1];
  const float* b_in   = (const float*)d_in[2];
  const float* ln_g   = (const float*)d_in[3];
  const float* ln_b   = (const float*)d_in[4];
  const float* W1     = (const float*)d_in[5];
  const float* b1     = (const float*)d_in[6];
  const float* W2     = (const float*)d_in[7];
  const float* b2     = (const float*)d_in[8];
  const float* W_head = (const float*)d_in[9];
  const float* b_head = (const float*)d_in[10];
  float* out = (float*)d_out;
  const int B = in_sizes[0] / 512;

  char* ws = (char*)d_ws;
  u16*   Wt_in3 = (u16*)ws;                 // 262144
  u16*   Wt_hd3 = Wt_in3 + 262144;          // 262144
  u16*   gw1f   = Wt_hd3 + 262144;          // 20480
  u16*   updA   = gw1f + 20480;             // 32768
  float* Up     = (float*)(updA + 32768);   // 32
  float* Vp     = Up + 32;                  // 32

  prep_k<<<2256, 256, 0, stream>>>(W_in, W_head, ln_g, W1, W2, b2, Wt_in3, Wt_hd3, gw1f, updA);
  uv_k<<<32, 64, 0, stream>>>(ln_g, ln_b, W1, b1, Up, Vp);
  fused_k<<<B / 128, 512, 0, stream>>>(x, Wt_in3, b_in, Wt_hd3, b_head, gw1f, updA, Up, Vp, out);
}